// Round 6
// baseline (372.481 us; speedup 1.0000x reference)
//
#include <hip/hip_runtime.h>

typedef unsigned short u16;
typedef unsigned int u32;
typedef __attribute__((ext_vector_type(8))) __bf16 bf16x8;
typedef __attribute__((ext_vector_type(4))) float f32x4;

#define BK 32

__device__ __forceinline__ u16 f2bf(float x) {
    u32 u = __float_as_uint(x);
    u = (u + 0x7FFFu + ((u >> 16) & 1u)) >> 16;
    return (u16)u;
}
__device__ __forceinline__ float bf2f(u16 h) { return __uint_as_float(((u32)h) << 16); }

#define GLD16(g, l)                                                                        \
    __builtin_amdgcn_global_load_lds((const __attribute__((address_space(1))) void*)(g),   \
                                     (__attribute__((address_space(3))) void*)(l), 16, 0, 0)

// counted vmcnt wait (compile-time literal), compiler-fenced
template <int N>
__device__ __forceinline__ void vm_wait() {
    if constexpr (N == 0) asm volatile("s_waitcnt vmcnt(0)" ::: "memory");
    else if constexpr (N == 1) asm volatile("s_waitcnt vmcnt(1)" ::: "memory");
    else if constexpr (N == 2) asm volatile("s_waitcnt vmcnt(2)" ::: "memory");
    else if constexpr (N == 3) asm volatile("s_waitcnt vmcnt(3)" ::: "memory");
    else if constexpr (N == 4) asm volatile("s_waitcnt vmcnt(4)" ::: "memory");
    else if constexpr (N == 6) asm volatile("s_waitcnt vmcnt(6)" ::: "memory");
    else if constexpr (N == 8) asm volatile("s_waitcnt vmcnt(8)" ::: "memory");
    else static_assert(N == 0, "unsupported vmcnt literal");
}
#define SBAR() asm volatile("s_barrier" ::: "memory")
#define LGKM0() asm volatile("s_waitcnt lgkmcnt(0)" ::: "memory")

// ---------------- fused prep: input fp32->bf16 hi/lo splits + 4 weight transpose-splits ----------------
__global__ __launch_bounds__(256) void prep_k(
    const float* __restrict__ q, const float* __restrict__ kv,
    u16* __restrict__ QXh, u16* __restrict__ QXl,
    u16* __restrict__ KVh, u16* __restrict__ KVl, long nblk, long n4,
    const float* __restrict__ Wq, const float* __restrict__ Wk,
    const float* __restrict__ Wv, const float* __restrict__ Wo,
    u16* __restrict__ WqTh, u16* __restrict__ WqTl,
    u16* __restrict__ WkvTh, u16* __restrict__ WkvTl,
    u16* __restrict__ WoTh, u16* __restrict__ WoTl, int dim) {
    long b = blockIdx.x;
    if (b < 2 * nblk) {
        const float* x = q; u16* h = QXh; u16* l = QXl;
        if (b >= nblk) { b -= nblk; x = kv; h = KVh; l = KVl; }
        long i = b * 256 + threadIdx.x;
        if (i >= n4) return;
        float4 v = ((const float4*)x)[i];
        float xs[4] = {v.x, v.y, v.z, v.w};
        u16 hh[4], ll[4];
#pragma unroll
        for (int qq = 0; qq < 4; ++qq) {
            hh[qq] = f2bf(xs[qq]);
            ll[qq] = f2bf(xs[qq] - bf2f(hh[qq]));
        }
        uint2 ph, pl;
        ph.x = hh[0] | ((u32)hh[1] << 16); ph.y = hh[2] | ((u32)hh[3] << 16);
        pl.x = ll[0] | ((u32)ll[1] << 16); pl.y = ll[2] | ((u32)ll[3] << 16);
        ((uint2*)h)[i] = ph;
        ((uint2*)l)[i] = pl;
        return;
    }
    long tb = b - 2 * nblk;
    const int z = (int)(tb >> 8);
    const int rem = (int)(tb & 255);
    const long DD = (long)dim * dim;
    const float* W; u16* Th; u16* Tl;
    switch (z) {
        case 0: W = Wq; Th = WqTh; Tl = WqTl; break;
        case 1: W = Wk; Th = WkvTh; Tl = WkvTl; break;
        case 2: W = Wv; Th = WkvTh + DD; Tl = WkvTl + DD; break;
        default: W = Wo; Th = WoTh; Tl = WoTl; break;
    }
    __shared__ float tile[32][33];
    const int bx = (rem & 15) * 32;
    const int by = (rem >> 4) * 32;
    const int tx = threadIdx.x & 31, ty = threadIdx.x >> 5;
    for (int i = 0; i < 32; i += 8)
        tile[ty + i][tx] = W[(size_t)(by + ty + i) * dim + bx + tx];
    __syncthreads();
    for (int i = 0; i < 32; i += 8) {
        float x = tile[tx][ty + i];
        u16 h = f2bf(x);
        size_t idx = (size_t)(bx + ty + i) * dim + by + tx;
        Th[idx] = h;
        Tl[idx] = f2bf(x - bf2f(h));
    }
}

// ---------------- row softmax, fp32 in, bf16 out in place ----------------
__global__ __launch_bounds__(256) void softmax_k(float* __restrict__ S, int N) {
    float* row = S + (size_t)blockIdx.x * N;
    const int t = threadIdx.x;
    float4 va = ((const float4*)row)[2 * t];
    float4 vb = ((const float4*)row)[2 * t + 1];
    float v[8] = {va.x, va.y, va.z, va.w, vb.x, vb.y, vb.z, vb.w};
    float m = v[0];
#pragma unroll
    for (int i = 1; i < 8; i++) m = fmaxf(m, v[i]);
#pragma unroll
    for (int o = 32; o; o >>= 1) m = fmaxf(m, __shfl_xor(m, o));
    __shared__ float smax[4], ssum[4];
    if ((t & 63) == 0) smax[t >> 6] = m;
    __syncthreads();
    m = fmaxf(fmaxf(smax[0], smax[1]), fmaxf(smax[2], smax[3]));
    float s = 0.f;
#pragma unroll
    for (int i = 0; i < 8; i++) { v[i] = __expf(v[i] - m); s += v[i]; }
#pragma unroll
    for (int o = 32; o; o >>= 1) s += __shfl_xor(s, o);
    if ((t & 63) == 0) ssum[t >> 6] = s;
    __syncthreads();
    s = ssum[0] + ssum[1] + ssum[2] + ssum[3];
    const float inv = 1.0f / s;
    u32 w0 = f2bf(v[0] * inv) | ((u32)f2bf(v[1] * inv) << 16);
    u32 w1 = f2bf(v[2] * inv) | ((u32)f2bf(v[3] * inv) << 16);
    u32 w2 = f2bf(v[4] * inv) | ((u32)f2bf(v[5] * inv) << 16);
    u32 w3 = f2bf(v[6] * inv) | ((u32)f2bf(v[7] * inv) << 16);
    uint4 o4; o4.x = w0; o4.y = w1; o4.z = w2; o4.w = w3;
    ((uint4*)row)[t] = o4;
}

// ---------------- MFMA GEMM, C = A @ BT^T ----------------
// v6 schedule, per K-step (2 barriers, race structure unchanged vs v4/v5):
//   vm_wait(NLD); SBAR;                 // tile t staged & visible
//   ds_read ALL frags; lgkmcnt(0); SBAR; // buffer free for overwrite
//   stage(t+2);                          // DMA issue overlaps MFMAs (early, T14-style)
//   sched_barrier(0); setprio(1); MFMA cluster; setprio(0);   // pure-reg, T5 role-split
// Correctness: barrier #2 is only crossed after every wave's lgkmcnt(0) -> all reads in
// VGPRs; the overwriting DMA for t+2 is issued strictly after that barrier.
struct GemmArgs {
    const u16 *Ah, *Al; long lda, strideA;
    const u16 *BTh, *BTl; long ldb, strideBT;
    const float *bias1, *bias2; int nsplit;
    const float* resid; long ldres; float scale;
    float* Cf; long ldcf;
    u16 *Cbh, *Cbl; long ldcb;
    u16* CbT; long tRows, tChans, ldct;
    long strideC; int K;
};

template <int SPLIT, int BMt, int BNt>
struct SmemT {
    u16 AsH[2][BMt * BK];
    u16 BsH[2][BNt * BK];
    u16 AsL[2][(SPLIT ? BMt : 1) * BK];
    u16 BsL[2][(SPLIT ? BNt : 1) * BK];
};

template <int SPLIT, int BMt, int BNt, int WR, int WC>
__device__ __forceinline__ void gemm_body(SmemT<SPLIT, BMt, BNt>& sm, const GemmArgs& g,
                                          int bxi, int byi, long bz) {
    static_assert(WR * WC == 4, "4 waves");
    constexpr int MI = BMt / WR / 16;
    constexpr int NJ = BNt / WC / 16;
    constexpr int PA = BMt / 64;
    constexpr int PB = BNt / 64;
    constexpr int NLD = (PA + PB) * (SPLIT ? 2 : 1);

    const u16* Ah = g.Ah + bz * g.strideA;
    const u16* BTh = g.BTh + bz * g.strideBT;
    const u16* Al = nullptr; const u16* BTl = nullptr;
    if constexpr (SPLIT) { Al = g.Al + bz * g.strideA; BTl = g.BTl + bz * g.strideBT; }
    float* Cf = g.Cf ? g.Cf + bz * g.strideC : nullptr;
    u16* Cbh = g.Cbh ? g.Cbh + bz * g.strideC : nullptr;
    u16* Cbl = g.Cbl ? g.Cbl + bz * g.strideC : nullptr;

    const int t = threadIdx.x;
    const int w = t >> 6, lane = t & 63;
    const int l15 = lane & 15, quad = lane >> 4;
    const int m0 = bxi * BMt, n0 = byi * BNt;
    const int wrow = (w / WC) * (BMt / WR);
    const int wcol = (w % WC) * (BNt / WC);

    // staging addresses (lane slot -> LDS slot is identity; lane FETCHES the swizzled col)
    const u16* gAh[PA]; const u16* gAl[PA]; int lA[PA];
    const u16* gBh[PB]; const u16* gBl[PB]; int lB[PB];
#pragma unroll
    for (int p = 0; p < PA; ++p) {
        int slot = p * 256 + t;
        int r = slot >> 2, c = slot & 3;
        int cg = c ^ ((r >> 1) & 3);
        gAh[p] = Ah + (long)(m0 + r) * g.lda + cg * 8;
        if constexpr (SPLIT) gAl[p] = Al + (long)(m0 + r) * g.lda + cg * 8;
        lA[p] = (p * 256 + w * 64) * 8;
    }
#pragma unroll
    for (int p = 0; p < PB; ++p) {
        int slot = p * 256 + t;
        int r = slot >> 2, c = slot & 3;
        int cg = c ^ ((r >> 1) & 3);
        gBh[p] = BTh + (long)(n0 + r) * g.ldb + cg * 8;
        if constexpr (SPLIT) gBl[p] = BTl + (long)(n0 + r) * g.ldb + cg * 8;
        lB[p] = (p * 256 + w * 64) * 8;
    }

    // fragment LDS offsets (u16 idx), constant across k-steps
    int aoff[MI], boff[NJ];
#pragma unroll
    for (int i = 0; i < MI; ++i) {
        int r = wrow + i * 16 + l15;
        aoff[i] = (r * 4 + (quad ^ ((r >> 1) & 3))) * 8;
    }
#pragma unroll
    for (int j = 0; j < NJ; ++j) {
        int r = wcol + j * 16 + l15;
        boff[j] = (r * 4 + (quad ^ ((r >> 1) & 3))) * 8;
    }

    f32x4 acc[MI][NJ];
#pragma unroll
    for (int i = 0; i < MI; i++)
#pragma unroll
        for (int j = 0; j < NJ; j++) acc[i][j] = (f32x4){0.f, 0.f, 0.f, 0.f};

    auto stage = [&](int buf) {
#pragma unroll
        for (int p = 0; p < PA; ++p) {
            GLD16(gAh[p], &sm.AsH[buf][lA[p]]);
            gAh[p] += BK;
            if constexpr (SPLIT) { GLD16(gAl[p], &sm.AsL[buf][lA[p]]); gAl[p] += BK; }
        }
#pragma unroll
        for (int p = 0; p < PB; ++p) {
            GLD16(gBh[p], &sm.BsH[buf][lB[p]]);
            gBh[p] += BK;
            if constexpr (SPLIT) { GLD16(gBl[p], &sm.BsL[buf][lB[p]]); gBl[p] += BK; }
        }
    };

    bf16x8 aH[MI], bH[NJ];
    bf16x8 aL[SPLIT ? MI : 1], bL[SPLIT ? NJ : 1];

    auto read_frags = [&](int buf) {
#pragma unroll
        for (int i = 0; i < MI; ++i) aH[i] = *(const bf16x8*)&sm.AsH[buf][aoff[i]];
#pragma unroll
        for (int j = 0; j < NJ; ++j) bH[j] = *(const bf16x8*)&sm.BsH[buf][boff[j]];
        if constexpr (SPLIT) {
#pragma unroll
            for (int i = 0; i < MI; ++i) aL[i] = *(const bf16x8*)&sm.AsL[buf][aoff[i]];
#pragma unroll
            for (int j = 0; j < NJ; ++j) bL[j] = *(const bf16x8*)&sm.BsL[buf][boff[j]];
        }
    };

    auto mfma_all = [&]() {
        if constexpr (SPLIT) {
#pragma unroll
            for (int i = 0; i < MI; ++i)
#pragma unroll
                for (int j = 0; j < NJ; ++j) {
                    acc[i][j] = __builtin_amdgcn_mfma_f32_16x16x32_bf16(aH[i], bH[j], acc[i][j], 0, 0, 0);
                    acc[i][j] = __builtin_amdgcn_mfma_f32_16x16x32_bf16(aH[i], bL[j], acc[i][j], 0, 0, 0);
                    acc[i][j] = __builtin_amdgcn_mfma_f32_16x16x32_bf16(aL[i], bH[j], acc[i][j], 0, 0, 0);
                }
        } else {
#pragma unroll
            for (int i = 0; i < MI; ++i)
#pragma unroll
                for (int j = 0; j < NJ; ++j)
                    acc[i][j] = __builtin_amdgcn_mfma_f32_16x16x32_bf16(aH[i], bH[j], acc[i][j], 0, 0, 0);
        }
    };

    const int nt = g.K / BK;  // >= 2 and even for all shapes used here
    stage(0);
    if (nt > 1) stage(1);
    for (int tt = 0; tt < nt; tt += 2) {
        // ---- tile tt in buf 0 ----
        if (tt + 1 < nt) vm_wait<NLD>(); else vm_wait<0>();
        SBAR();
        read_frags(0);
        LGKM0();
        SBAR();
        if (tt + 2 < nt) stage(0);
        __builtin_amdgcn_sched_barrier(0);
        __builtin_amdgcn_s_setprio(1);
        mfma_all();
        __builtin_amdgcn_s_setprio(0);
        // ---- tile tt+1 in buf 1 ----
        if (tt + 1 < nt) {
            if (tt + 2 < nt) vm_wait<NLD>(); else vm_wait<0>();
            SBAR();
            read_frags(1);
            LGKM0();
            SBAR();
            if (tt + 3 < nt) stage(1);
            __builtin_amdgcn_sched_barrier(0);
            __builtin_amdgcn_s_setprio(1);
            mfma_all();
            __builtin_amdgcn_s_setprio(0);
        }
    }

    // epilogue: C/D layout col=lane&15, row=quad*4+reg
#pragma unroll
    for (int i = 0; i < MI; ++i) {
#pragma unroll
        for (int j = 0; j < NJ; ++j) {
            const int mBase = m0 + wrow + i * 16 + quad * 4;
            const int nn = n0 + wcol + j * 16 + l15;
            const bool norm = nn < g.nsplit;
            float bvs;
            if (norm) bvs = g.bias1 ? g.bias1[nn] : 0.f;
            else bvs = g.bias2 ? g.bias2[nn - g.nsplit] : 0.f;
#pragma unroll
            for (int r = 0; r < 4; ++r) {
                const long row = mBase + r;
                float x = acc[i][j][r] * g.scale + bvs;
                if (g.resid) x += g.resid[row * g.ldres + nn];
                if (norm) {
                    if (Cf) Cf[row * g.ldcf + nn] = x;
                    if (Cbh) {
                        u16 h = f2bf(x);
                        Cbh[row * g.ldcb + nn] = h;
                        if (Cbl) Cbl[row * g.ldcb + nn] = f2bf(x - bf2f(h));
                    }
                } else {
                    long b = row / g.tRows, qq = row - b * g.tRows;
                    g.CbT[(b * g.tChans + (nn - g.nsplit)) * g.ldct + qq] = f2bf(x);
                }
            }
        }
    }
}

template <int SPLIT, int BMt, int BNt, int WR, int WC>
__global__ __launch_bounds__(256) void gemm_k(GemmArgs g) {
    __shared__ SmemT<SPLIT, BMt, BNt> sm;
    gemm_body<SPLIT, BMt, BNt, WR, WC>(sm, g, blockIdx.x, blockIdx.y, blockIdx.z);
}

// two independent GEMMs (same config) in one dispatch, y-concatenated
template <int SPLIT, int BMt, int BNt, int WR, int WC>
__global__ __launch_bounds__(256) void gemm2_k(GemmArgs g0, int ny0, GemmArgs g1) {
    __shared__ SmemT<SPLIT, BMt, BNt> sm;
    if ((int)blockIdx.y < ny0)
        gemm_body<SPLIT, BMt, BNt, WR, WC>(sm, g0, blockIdx.x, blockIdx.y, blockIdx.z);
    else
        gemm_body<SPLIT, BMt, BNt, WR, WC>(sm, g1, blockIdx.x, blockIdx.y - ny0, blockIdx.z);
}

extern "C" void kernel_launch(void* const* d_in, const int* in_sizes, int n_in,
                              void* d_out, int out_size, void* d_ws, size_t ws_size,
                              hipStream_t stream) {
    const float* query = (const float*)d_in[0];
    const float* kv    = (const float*)d_in[1];
    const float* Wq = (const float*)d_in[2];
    const float* bq = (const float*)d_in[3];
    const float* Wk = (const float*)d_in[4];
    const float* bk = (const float*)d_in[5];
    const float* Wv = (const float*)d_in[6];
    const float* bv = (const float*)d_in[7];
    const float* Wo = (const float*)d_in[8];
    const float* bo = (const float*)d_in[9];
    float* out = (float*)d_out;

    const int B = 4, N = 2048, D = 512;
    const long MD = (long)B * N * D;  // 4,194,304 (8192 rows x 512)
    const int BIG = 1 << 30;

    char* p = (char*)d_ws;
    auto alloc = [&](size_t bytes) { void* r = (void*)p; p += (bytes + 255) & ~(size_t)255; return r; };
    float* S = (float*)alloc((long)B * N * N * 4);   // 67 MB; fp32 scores, bf16 P in place
    u16* QXh = (u16*)S;                               // input splits alias S (dead before S written)
    u16* QXl = QXh + MD;
    u16* KVh = QXl + MD;
    u16* KVl = KVh + MD;
    u16* Qh = (u16*)alloc(MD * 2);
    u16* Ql = (u16*)alloc(MD * 2);
    u16* Kh = (u16*)alloc(MD * 2);
    u16* Kl = (u16*)alloc(MD * 2);
    u16* Vt = (u16*)alloc(MD * 2);                    // [B][D][N]
    u16* Oh = (u16*)alloc(MD * 2);
    u16* WqTh = (u16*)alloc((long)D * D * 2);
    u16* WqTl = (u16*)alloc((long)D * D * 2);
    u16* WkvTh = (u16*)alloc((long)2 * D * D * 2);
    u16* WkvTl = (u16*)alloc((long)2 * D * D * 2);
    u16* WoTh = (u16*)alloc((long)D * D * 2);
    u16* WoTl = (u16*)alloc((long)D * D * 2);

    const dim3 blk(256, 1, 1);
    const float SCALE = 22.627416997969522f;  // sqrt(512), multiplied per reference

    prep_k<<<dim3(2 * 4096 + 1024, 1, 1), blk, 0, stream>>>(
        query, kv, QXh, QXl, KVh, KVl, 4096, MD / 4,
        Wq, Wk, Wv, Wo, WqTh, WqTl, WkvTh, WkvTl, WoTh, WoTl, D);

    // merged Q-proj (y<8) + KV-proj (y>=8): 1536 blocks = exactly 2 rounds at 3 blocks/CU
    GemmArgs qa{};
    qa.Ah = QXh; qa.Al = QXl; qa.lda = D; qa.strideA = 0;
    qa.BTh = WqTh; qa.BTl = WqTl; qa.ldb = D; qa.strideBT = 0;
    qa.bias1 = bq; qa.bias2 = nullptr; qa.nsplit = BIG;
    qa.resid = nullptr; qa.ldres = 0; qa.scale = 1.0f;
    qa.Cf = nullptr; qa.ldcf = 0;
    qa.Cbh = Qh; qa.Cbl = Ql; qa.ldcb = D;
    qa.CbT = nullptr; qa.tRows = 1; qa.tChans = 1; qa.ldct = 1;
    qa.strideC = 0; qa.K = D;

    GemmArgs ka{};
    ka.Ah = KVh; ka.Al = KVl; ka.lda = D; ka.strideA = 0;
    ka.BTh = WkvTh; ka.BTl = WkvTl; ka.ldb = D; ka.strideBT = 0;
    ka.bias1 = bk; ka.bias2 = bv; ka.nsplit = D;
    ka.resid = nullptr; ka.ldres = 0; ka.scale = 1.0f;
    ka.Cf = nullptr; ka.ldcf = 0;
    ka.Cbh = Kh; ka.Cbl = Kl; ka.ldcb = D;
    ka.CbT = Vt; ka.tRows = N; ka.tChans = D; ka.ldct = N;
    ka.strideC = 0; ka.K = D;
    gemm2_k<1, 128, 64, 2, 2><<<dim3(64, 24, 1), blk, 0, stream>>>(qa, 8, ka);

    // S = SCALE * Q @ K^T  [128x64 SPLIT, 48 KiB -> 3 blocks/CU]
    GemmArgs sa{};
    sa.Ah = Qh; sa.Al = Ql; sa.lda = D; sa.strideA = (long)N * D;
    sa.BTh = Kh; sa.BTl = Kl; sa.ldb = D; sa.strideBT = (long)N * D;
    sa.bias1 = nullptr; sa.bias2 = nullptr; sa.nsplit = BIG;
    sa.resid = nullptr; sa.ldres = 0; sa.scale = SCALE;
    sa.Cf = S; sa.ldcf = N;
    sa.Cbh = nullptr; sa.Cbl = nullptr; sa.ldcb = 0;
    sa.CbT = nullptr; sa.tRows = 1; sa.tChans = 1; sa.ldct = 1;
    sa.strideC = (long)N * N; sa.K = D;
    gemm_k<1, 128, 64, 2, 2><<<dim3(16, 32, 4), blk, 0, stream>>>(sa);

    softmax_k<<<dim3(B * N, 1, 1), blk, 0, stream>>>(S, N);

    // O = P @ V  [128x64 non-split, K=2048]
    GemmArgs pa{};
    pa.Ah = (const u16*)S; pa.Al = nullptr; pa.lda = 2L * N; pa.strideA = (long)N * 2 * N;
    pa.BTh = Vt; pa.BTl = nullptr; pa.ldb = N; pa.strideBT = (long)D * N;
    pa.bias1 = nullptr; pa.bias2 = nullptr; pa.nsplit = BIG;
    pa.resid = nullptr; pa.ldres = 0; pa.scale = 1.0f;
    pa.Cf = nullptr; pa.ldcf = 0;
    pa.Cbh = Oh; pa.Cbl = nullptr; pa.ldcb = D;
    pa.CbT = nullptr; pa.tRows = 1; pa.tChans = 1; pa.ldct = 1;
    pa.strideC = (long)N * D; pa.K = N;
    gemm_k<0, 128, 64, 2, 2><<<dim3(16, 8, 4), blk, 0, stream>>>(pa);

    // out = query + O @ Wo + bo
    GemmArgs oa{};
    oa.Ah = Oh; oa.Al = nullptr; oa.lda = D; oa.strideA = 0;
    oa.BTh = WoTh; oa.BTl = nullptr; oa.ldb = D; oa.strideBT = 0;
    oa.bias1 = bo; oa.bias2 = nullptr; oa.nsplit = BIG;
    oa.resid = query; oa.ldres = D; oa.scale = 1.0f;
    oa.Cf = out; oa.ldcf = D;
    oa.Cbh = nullptr; oa.Cbl = nullptr; oa.ldcb = 0;
    oa.CbT = nullptr; oa.tRows = 1; oa.tChans = 1; oa.ldct = 1;
    oa.strideC = 0; oa.K = D;
    gemm_k<0, 128, 64, 2, 2><<<dim3(64, 8, 1), blk, 0, stream>>>(oa);

    (void)in_sizes; (void)n_in; (void)out_size; (void)ws_size;
}

// Round 7
// 330.377 us; speedup vs baseline: 1.1274x; 1.1274x over previous
//
#include <hip/hip_runtime.h>

typedef unsigned short u16;
typedef unsigned int u32;
typedef __attribute__((ext_vector_type(8))) __bf16 bf16x8;
typedef __attribute__((ext_vector_type(4))) float f32x4;

#define BK 32

__device__ __forceinline__ u16 f2bf(float x) {
    u32 u = __float_as_uint(x);
    u = (u + 0x7FFFu + ((u >> 16) & 1u)) >> 16;
    return (u16)u;
}
__device__ __forceinline__ float bf2f(u16 h) { return __uint_as_float(((u32)h) << 16); }

#define GLD16(g, l)                                                                        \
    __builtin_amdgcn_global_load_lds((const __attribute__((address_space(1))) void*)(g),   \
                                     (__attribute__((address_space(3))) void*)(l), 16, 0, 0)

// counted vmcnt wait (compile-time literal), compiler-fenced
template <int N>
__device__ __forceinline__ void vm_wait() {
    if constexpr (N == 0) asm volatile("s_waitcnt vmcnt(0)" ::: "memory");
    else if constexpr (N == 1) asm volatile("s_waitcnt vmcnt(1)" ::: "memory");
    else if constexpr (N == 2) asm volatile("s_waitcnt vmcnt(2)" ::: "memory");
    else if constexpr (N == 3) asm volatile("s_waitcnt vmcnt(3)" ::: "memory");
    else if constexpr (N == 4) asm volatile("s_waitcnt vmcnt(4)" ::: "memory");
    else if constexpr (N == 6) asm volatile("s_waitcnt vmcnt(6)" ::: "memory");
    else if constexpr (N == 8) asm volatile("s_waitcnt vmcnt(8)" ::: "memory");
    else static_assert(N == 0, "unsupported vmcnt literal");
}
#define SBAR() asm volatile("s_barrier" ::: "memory")

// ---------------- fused prep: input fp32->bf16 hi/lo splits + 4 weight transpose-splits ----------------
__global__ __launch_bounds__(256) void prep_k(
    const float* __restrict__ q, const float* __restrict__ kv,
    u16* __restrict__ QXh, u16* __restrict__ QXl,
    u16* __restrict__ KVh, u16* __restrict__ KVl, long nblk, long n4,
    const float* __restrict__ Wq, const float* __restrict__ Wk,
    const float* __restrict__ Wv, const float* __restrict__ Wo,
    u16* __restrict__ WqTh, u16* __restrict__ WqTl,
    u16* __restrict__ WkvTh, u16* __restrict__ WkvTl,
    u16* __restrict__ WoTh, u16* __restrict__ WoTl, int dim) {
    long b = blockIdx.x;
    if (b < 2 * nblk) {
        const float* x = q; u16* h = QXh; u16* l = QXl;
        if (b >= nblk) { b -= nblk; x = kv; h = KVh; l = KVl; }
        long i = b * 256 + threadIdx.x;
        if (i >= n4) return;
        float4 v = ((const float4*)x)[i];
        float xs[4] = {v.x, v.y, v.z, v.w};
        u16 hh[4], ll[4];
#pragma unroll
        for (int qq = 0; qq < 4; ++qq) {
            hh[qq] = f2bf(xs[qq]);
            ll[qq] = f2bf(xs[qq] - bf2f(hh[qq]));
        }
        uint2 ph, pl;
        ph.x = hh[0] | ((u32)hh[1] << 16); ph.y = hh[2] | ((u32)hh[3] << 16);
        pl.x = ll[0] | ((u32)ll[1] << 16); pl.y = ll[2] | ((u32)ll[3] << 16);
        ((uint2*)h)[i] = ph;
        ((uint2*)l)[i] = pl;
        return;
    }
    long tb = b - 2 * nblk;
    const int z = (int)(tb >> 8);
    const int rem = (int)(tb & 255);
    const long DD = (long)dim * dim;
    const float* W; u16* Th; u16* Tl;
    switch (z) {
        case 0: W = Wq; Th = WqTh; Tl = WqTl; break;
        case 1: W = Wk; Th = WkvTh; Tl = WkvTl; break;
        case 2: W = Wv; Th = WkvTh + DD; Tl = WkvTl + DD; break;
        default: W = Wo; Th = WoTh; Tl = WoTl; break;
    }
    __shared__ float tile[32][33];
    const int bx = (rem & 15) * 32;
    const int by = (rem >> 4) * 32;
    const int tx = threadIdx.x & 31, ty = threadIdx.x >> 5;
    for (int i = 0; i < 32; i += 8)
        tile[ty + i][tx] = W[(size_t)(by + ty + i) * dim + bx + tx];
    __syncthreads();
    for (int i = 0; i < 32; i += 8) {
        float x = tile[tx][ty + i];
        u16 h = f2bf(x);
        size_t idx = (size_t)(bx + ty + i) * dim + by + tx;
        Th[idx] = h;
        Tl[idx] = f2bf(x - bf2f(h));
    }
}

// ---------------- row softmax, fp32 in, bf16 out in place ----------------
__global__ __launch_bounds__(256) void softmax_k(float* __restrict__ S, int N) {
    float* row = S + (size_t)blockIdx.x * N;
    const int t = threadIdx.x;
    float4 va = ((const float4*)row)[2 * t];
    float4 vb = ((const float4*)row)[2 * t + 1];
    float v[8] = {va.x, va.y, va.z, va.w, vb.x, vb.y, vb.z, vb.w};
    float m = v[0];
#pragma unroll
    for (int i = 1; i < 8; i++) m = fmaxf(m, v[i]);
#pragma unroll
    for (int o = 32; o; o >>= 1) m = fmaxf(m, __shfl_xor(m, o));
    __shared__ float smax[4], ssum[4];
    if ((t & 63) == 0) smax[t >> 6] = m;
    __syncthreads();
    m = fmaxf(fmaxf(smax[0], smax[1]), fmaxf(smax[2], smax[3]));
    float s = 0.f;
#pragma unroll
    for (int i = 0; i < 8; i++) { v[i] = __expf(v[i] - m); s += v[i]; }
#pragma unroll
    for (int o = 32; o; o >>= 1) s += __shfl_xor(s, o);
    if ((t & 63) == 0) ssum[t >> 6] = s;
    __syncthreads();
    s = ssum[0] + ssum[1] + ssum[2] + ssum[3];
    const float inv = 1.0f / s;
    u32 w0 = f2bf(v[0] * inv) | ((u32)f2bf(v[1] * inv) << 16);
    u32 w1 = f2bf(v[2] * inv) | ((u32)f2bf(v[3] * inv) << 16);
    u32 w2 = f2bf(v[4] * inv) | ((u32)f2bf(v[5] * inv) << 16);
    u32 w3 = f2bf(v[6] * inv) | ((u32)f2bf(v[7] * inv) << 16);
    uint4 o4; o4.x = w0; o4.y = w1; o4.z = w2; o4.w = w3;
    ((uint4*)row)[t] = o4;
}

// ---------------- MFMA GEMM, C = A @ BT^T ----------------
// v7 = v4/v5 schedule RESTORED (v6's read-cluster + lgkm0 + extra-barrier phase-split
// regressed 25-40%: it defeated the compiler's fine-grained lgkmcnt interleave and
// phase-aligned all waves onto the LDS port -- m141/m196-class mistake).
// Per K-step: {vm_wait(NLD); SBAR; compute (ds_read+MFMA, compiler-scheduled); SBAR;
// stage(t+2)} -- counted vmcnt never drains to 0 in the main loop.
struct GemmArgs {
    const u16 *Ah, *Al; long lda, strideA;
    const u16 *BTh, *BTl; long ldb, strideBT;
    const float *bias1, *bias2; int nsplit;
    const float* resid; long ldres; float scale;
    float* Cf; long ldcf;
    u16 *Cbh, *Cbl; long ldcb;
    u16* CbT; long tRows, tChans, ldct;
    long strideC; int K;
};

template <int SPLIT, int BMt, int BNt>
struct SmemT {
    u16 AsH[2][BMt * BK];
    u16 BsH[2][BNt * BK];
    u16 AsL[2][(SPLIT ? BMt : 1) * BK];
    u16 BsL[2][(SPLIT ? BNt : 1) * BK];
};

template <int SPLIT, int BMt, int BNt, int WR, int WC>
__device__ __forceinline__ void gemm_body(SmemT<SPLIT, BMt, BNt>& sm, const GemmArgs& g,
                                          int bxi, int byi, long bz) {
    static_assert(WR * WC == 4, "4 waves");
    constexpr int MI = BMt / WR / 16;
    constexpr int NJ = BNt / WC / 16;
    constexpr int PA = BMt / 64;
    constexpr int PB = BNt / 64;
    constexpr int NLD = (PA + PB) * (SPLIT ? 2 : 1);

    const u16* Ah = g.Ah + bz * g.strideA;
    const u16* BTh = g.BTh + bz * g.strideBT;
    const u16* Al = nullptr; const u16* BTl = nullptr;
    if constexpr (SPLIT) { Al = g.Al + bz * g.strideA; BTl = g.BTl + bz * g.strideBT; }
    float* Cf = g.Cf ? g.Cf + bz * g.strideC : nullptr;
    u16* Cbh = g.Cbh ? g.Cbh + bz * g.strideC : nullptr;
    u16* Cbl = g.Cbl ? g.Cbl + bz * g.strideC : nullptr;

    const int t = threadIdx.x;
    const int w = t >> 6, lane = t & 63;
    const int l15 = lane & 15, quad = lane >> 4;
    const int m0 = bxi * BMt, n0 = byi * BNt;
    const int wrow = (w / WC) * (BMt / WR);
    const int wcol = (w % WC) * (BNt / WC);

    // staging addresses (lane slot -> LDS slot is identity; lane FETCHES the swizzled col)
    const u16* gAh[PA]; const u16* gAl[PA]; int lA[PA];
    const u16* gBh[PB]; const u16* gBl[PB]; int lB[PB];
#pragma unroll
    for (int p = 0; p < PA; ++p) {
        int slot = p * 256 + t;
        int r = slot >> 2, c = slot & 3;
        int cg = c ^ ((r >> 1) & 3);
        gAh[p] = Ah + (long)(m0 + r) * g.lda + cg * 8;
        if constexpr (SPLIT) gAl[p] = Al + (long)(m0 + r) * g.lda + cg * 8;
        lA[p] = (p * 256 + w * 64) * 8;
    }
#pragma unroll
    for (int p = 0; p < PB; ++p) {
        int slot = p * 256 + t;
        int r = slot >> 2, c = slot & 3;
        int cg = c ^ ((r >> 1) & 3);
        gBh[p] = BTh + (long)(n0 + r) * g.ldb + cg * 8;
        if constexpr (SPLIT) gBl[p] = BTl + (long)(n0 + r) * g.ldb + cg * 8;
        lB[p] = (p * 256 + w * 64) * 8;
    }

    // fragment LDS offsets (u16 idx), constant across k-steps
    int aoff[MI], boff[NJ];
#pragma unroll
    for (int i = 0; i < MI; ++i) {
        int r = wrow + i * 16 + l15;
        aoff[i] = (r * 4 + (quad ^ ((r >> 1) & 3))) * 8;
    }
#pragma unroll
    for (int j = 0; j < NJ; ++j) {
        int r = wcol + j * 16 + l15;
        boff[j] = (r * 4 + (quad ^ ((r >> 1) & 3))) * 8;
    }

    f32x4 acc[MI][NJ];
#pragma unroll
    for (int i = 0; i < MI; i++)
#pragma unroll
        for (int j = 0; j < NJ; j++) acc[i][j] = (f32x4){0.f, 0.f, 0.f, 0.f};

    auto stage = [&](int buf) {
#pragma unroll
        for (int p = 0; p < PA; ++p) {
            GLD16(gAh[p], &sm.AsH[buf][lA[p]]);
            gAh[p] += BK;
            if constexpr (SPLIT) { GLD16(gAl[p], &sm.AsL[buf][lA[p]]); gAl[p] += BK; }
        }
#pragma unroll
        for (int p = 0; p < PB; ++p) {
            GLD16(gBh[p], &sm.BsH[buf][lB[p]]);
            gBh[p] += BK;
            if constexpr (SPLIT) { GLD16(gBl[p], &sm.BsL[buf][lB[p]]); gBl[p] += BK; }
        }
    };

    // ds_read fragments + MFMAs in one region -- compiler schedules fine-grained lgkmcnt
    auto compute = [&](int buf) {
        bf16x8 aH[MI], bH[NJ];
#pragma unroll
        for (int i = 0; i < MI; ++i) aH[i] = *(const bf16x8*)&sm.AsH[buf][aoff[i]];
#pragma unroll
        for (int j = 0; j < NJ; ++j) bH[j] = *(const bf16x8*)&sm.BsH[buf][boff[j]];
        if constexpr (SPLIT) {
            bf16x8 aL[MI], bL[NJ];
#pragma unroll
            for (int i = 0; i < MI; ++i) aL[i] = *(const bf16x8*)&sm.AsL[buf][aoff[i]];
#pragma unroll
            for (int j = 0; j < NJ; ++j) bL[j] = *(const bf16x8*)&sm.BsL[buf][boff[j]];
#pragma unroll
            for (int i = 0; i < MI; ++i)
#pragma unroll
                for (int j = 0; j < NJ; ++j) {
                    acc[i][j] = __builtin_amdgcn_mfma_f32_16x16x32_bf16(aH[i], bH[j], acc[i][j], 0, 0, 0);
                    acc[i][j] = __builtin_amdgcn_mfma_f32_16x16x32_bf16(aH[i], bL[j], acc[i][j], 0, 0, 0);
                    acc[i][j] = __builtin_amdgcn_mfma_f32_16x16x32_bf16(aL[i], bH[j], acc[i][j], 0, 0, 0);
                }
        } else {
#pragma unroll
            for (int i = 0; i < MI; ++i)
#pragma unroll
                for (int j = 0; j < NJ; ++j)
                    acc[i][j] = __builtin_amdgcn_mfma_f32_16x16x32_bf16(aH[i], bH[j], acc[i][j], 0, 0, 0);
        }
    };

    const int nt = g.K / BK;  // >= 2 and even for all shapes used here
    stage(0);
    if (nt > 1) stage(1);
    for (int tt = 0; tt < nt; tt += 2) {
        // ---- tile tt in buf 0 ----
        if (tt + 1 < nt) vm_wait<NLD>(); else vm_wait<0>();
        SBAR();
        compute(0);
        SBAR();
        if (tt + 2 < nt) stage(0);
        // ---- tile tt+1 in buf 1 ----
        if (tt + 1 < nt) {
            if (tt + 2 < nt) vm_wait<NLD>(); else vm_wait<0>();
            SBAR();
            compute(1);
            SBAR();
            if (tt + 3 < nt) stage(1);
        }
    }

    // epilogue: C/D layout col=lane&15, row=quad*4+reg
#pragma unroll
    for (int i = 0; i < MI; ++i) {
#pragma unroll
        for (int j = 0; j < NJ; ++j) {
            const int mBase = m0 + wrow + i * 16 + quad * 4;
            const int nn = n0 + wcol + j * 16 + l15;
            const bool norm = nn < g.nsplit;
            float bvs;
            if (norm) bvs = g.bias1 ? g.bias1[nn] : 0.f;
            else bvs = g.bias2 ? g.bias2[nn - g.nsplit] : 0.f;
#pragma unroll
            for (int r = 0; r < 4; ++r) {
                const long row = mBase + r;
                float x = acc[i][j][r] * g.scale + bvs;
                if (g.resid) x += g.resid[row * g.ldres + nn];
                if (norm) {
                    if (Cf) Cf[row * g.ldcf + nn] = x;
                    if (Cbh) {
                        u16 h = f2bf(x);
                        Cbh[row * g.ldcb + nn] = h;
                        if (Cbl) Cbl[row * g.ldcb + nn] = f2bf(x - bf2f(h));
                    }
                } else {
                    long b = row / g.tRows, qq = row - b * g.tRows;
                    g.CbT[(b * g.tChans + (nn - g.nsplit)) * g.ldct + qq] = f2bf(x);
                }
            }
        }
    }
}

template <int SPLIT, int BMt, int BNt, int WR, int WC>
__global__ __launch_bounds__(256) void gemm_k(GemmArgs g) {
    __shared__ SmemT<SPLIT, BMt, BNt> sm;
    gemm_body<SPLIT, BMt, BNt, WR, WC>(sm, g, blockIdx.x, blockIdx.y, blockIdx.z);
}

// two independent GEMMs (same config) in one dispatch, y-concatenated
template <int SPLIT, int BMt, int BNt, int WR, int WC>
__global__ __launch_bounds__(256) void gemm2_k(GemmArgs g0, int ny0, GemmArgs g1) {
    __shared__ SmemT<SPLIT, BMt, BNt> sm;
    if ((int)blockIdx.y < ny0)
        gemm_body<SPLIT, BMt, BNt, WR, WC>(sm, g0, blockIdx.x, blockIdx.y, blockIdx.z);
    else
        gemm_body<SPLIT, BMt, BNt, WR, WC>(sm, g1, blockIdx.x, blockIdx.y - ny0, blockIdx.z);
}

extern "C" void kernel_launch(void* const* d_in, const int* in_sizes, int n_in,
                              void* d_out, int out_size, void* d_ws, size_t ws_size,
                              hipStream_t stream) {
    const float* query = (const float*)d_in[0];
    const float* kv    = (const float*)d_in[1];
    const float* Wq = (const float*)d_in[2];
    const float* bq = (const float*)d_in[3];
    const float* Wk = (const float*)d_in[4];
    const float* bk = (const float*)d_in[5];
    const float* Wv = (const float*)d_in[6];
    const float* bv = (const float*)d_in[7];
    const float* Wo = (const float*)d_in[8];
    const float* bo = (const float*)d_in[9];
    float* out = (float*)d_out;

    const int B = 4, N = 2048, D = 512;
    const long MD = (long)B * N * D;  // 4,194,304 (8192 rows x 512)
    const int BIG = 1 << 30;

    char* p = (char*)d_ws;
    auto alloc = [&](size_t bytes) { void* r = (void*)p; p += (bytes + 255) & ~(size_t)255; return r; };
    float* S = (float*)alloc((long)B * N * N * 4);   // 67 MB; fp32 scores, bf16 P in place
    u16* QXh = (u16*)S;                               // input splits alias S (dead before S written)
    u16* QXl = QXh + MD;
    u16* KVh = QXl + MD;
    u16* KVl = KVh + MD;
    u16* Qh = (u16*)alloc(MD * 2);
    u16* Ql = (u16*)alloc(MD * 2);
    u16* Kh = (u16*)alloc(MD * 2);
    u16* Kl = (u16*)alloc(MD * 2);
    u16* Vt = (u16*)alloc(MD * 2);                    // [B][D][N]
    u16* Oh = (u16*)alloc(MD * 2);
    u16* WqTh = (u16*)alloc((long)D * D * 2);
    u16* WqTl = (u16*)alloc((long)D * D * 2);
    u16* WkvTh = (u16*)alloc((long)2 * D * D * 2);
    u16* WkvTl = (u16*)alloc((long)2 * D * D * 2);
    u16* WoTh = (u16*)alloc((long)D * D * 2);
    u16* WoTl = (u16*)alloc((long)D * D * 2);

    const dim3 blk(256, 1, 1);
    const float SCALE = 22.627416997969522f;  // sqrt(512), multiplied per reference

    prep_k<<<dim3(2 * 4096 + 1024, 1, 1), blk, 0, stream>>>(
        query, kv, QXh, QXl, KVh, KVl, 4096, MD / 4,
        Wq, Wk, Wv, Wo, WqTh, WqTl, WkvTh, WkvTl, WoTh, WoTl, D);

    // merged Q-proj (y<8) + KV-proj (y>=8): 1536 blocks = exactly 2 rounds at 3 blocks/CU
    GemmArgs qa{};
    qa.Ah = QXh; qa.Al = QXl; qa.lda = D; qa.strideA = 0;
    qa.BTh = WqTh; qa.BTl = WqTl; qa.ldb = D; qa.strideBT = 0;
    qa.bias1 = bq; qa.bias2 = nullptr; qa.nsplit = BIG;
    qa.resid = nullptr; qa.ldres = 0; qa.scale = 1.0f;
    qa.Cf = nullptr; qa.ldcf = 0;
    qa.Cbh = Qh; qa.Cbl = Ql; qa.ldcb = D;
    qa.CbT = nullptr; qa.tRows = 1; qa.tChans = 1; qa.ldct = 1;
    qa.strideC = 0; qa.K = D;

    GemmArgs ka{};
    ka.Ah = KVh; ka.Al = KVl; ka.lda = D; ka.strideA = 0;
    ka.BTh = WkvTh; ka.BTl = WkvTl; ka.ldb = D; ka.strideBT = 0;
    ka.bias1 = bk; ka.bias2 = bv; ka.nsplit = D;
    ka.resid = nullptr; ka.ldres = 0; ka.scale = 1.0f;
    ka.Cf = nullptr; ka.ldcf = 0;
    ka.Cbh = Kh; ka.Cbl = Kl; ka.ldcb = D;
    ka.CbT = Vt; ka.tRows = N; ka.tChans = D; ka.ldct = N;
    ka.strideC = 0; ka.K = D;
    gemm2_k<1, 128, 64, 2, 2><<<dim3(64, 24, 1), blk, 0, stream>>>(qa, 8, ka);

    // S = SCALE * Q @ K^T  [128x64 SPLIT, 48 KiB -> 3 blocks/CU]
    GemmArgs sa{};
    sa.Ah = Qh; sa.Al = Ql; sa.lda = D; sa.strideA = (long)N * D;
    sa.BTh = Kh; sa.BTl = Kl; sa.ldb = D; sa.strideBT = (long)N * D;
    sa.bias1 = nullptr; sa.bias2 = nullptr; sa.nsplit = BIG;
    sa.resid = nullptr; sa.ldres = 0; sa.scale = SCALE;
    sa.Cf = S; sa.ldcf = N;
    sa.Cbh = nullptr; sa.Cbl = nullptr; sa.ldcb = 0;
    sa.CbT = nullptr; sa.tRows = 1; sa.tChans = 1; sa.ldct = 1;
    sa.strideC = (long)N * N; sa.K = D;
    gemm_k<1, 128, 64, 2, 2><<<dim3(16, 32, 4), blk, 0, stream>>>(sa);

    softmax_k<<<dim3(B * N, 1, 1), blk, 0, stream>>>(S, N);

    // O = P @ V  [128x64 non-split, K=2048]
    GemmArgs pa{};
    pa.Ah = (const u16*)S; pa.Al = nullptr; pa.lda = 2L * N; pa.strideA = (long)N * 2 * N;
    pa.BTh = Vt; pa.BTl = nullptr; pa.ldb = N; pa.strideBT = (long)D * N;
    pa.bias1 = nullptr; pa.bias2 = nullptr; pa.nsplit = BIG;
    pa.resid = nullptr; pa.ldres = 0; pa.scale = 1.0f;
    pa.Cf = nullptr; pa.ldcf = 0;
    pa.Cbh = Oh; pa.Cbl = nullptr; pa.ldcb = D;
    pa.CbT = nullptr; pa.tRows = 1; pa.tChans = 1; pa.ldct = 1;
    pa.strideC = (long)N * D; pa.K = N;
    gemm_k<0, 128, 64, 2, 2><<<dim3(16, 8, 4), blk, 0, stream>>>(pa);

    // out = query + O @ Wo + bo
    GemmArgs oa{};
    oa.Ah = Oh; oa.Al = nullptr; oa.lda = D; oa.strideA = 0;
    oa.BTh = WoTh; oa.BTl = nullptr; oa.ldb = D; oa.strideBT = 0;
    oa.bias1 = bo; oa.bias2 = nullptr; oa.nsplit = BIG;
    oa.resid = query; oa.ldres = D; oa.scale = 1.0f;
    oa.Cf = out; oa.ldcf = D;
    oa.Cbh = nullptr; oa.Cbl = nullptr; oa.ldcb = 0;
    oa.CbT = nullptr; oa.tRows = 1; oa.tChans = 1; oa.ldct = 1;
    oa.strideC = 0; oa.K = D;
    gemm_k<0, 128, 64, 2, 2><<<dim3(64, 8, 1), blk, 0, stream>>>(oa);

    (void)in_sizes; (void)n_in; (void)out_size; (void)ws_size;
}

// Round 8
// 279.826 us; speedup vs baseline: 1.3311x; 1.1806x over previous
//
#include <hip/hip_runtime.h>

typedef unsigned short u16;
typedef unsigned int u32;
typedef __attribute__((ext_vector_type(8))) __bf16 bf16x8;
typedef __attribute__((ext_vector_type(4))) float f32x4;

#define BK 32

__device__ __forceinline__ u16 f2bf(float x) {
    u32 u = __float_as_uint(x);
    u = (u + 0x7FFFu + ((u >> 16) & 1u)) >> 16;
    return (u16)u;
}
__device__ __forceinline__ float bf2f(u16 h) { return __uint_as_float(((u32)h) << 16); }

#define GLD16(g, l)                                                                        \
    __builtin_amdgcn_global_load_lds((const __attribute__((address_space(1))) void*)(g),   \
                                     (__attribute__((address_space(3))) void*)(l), 16, 0, 0)

// counted vmcnt wait (compile-time literal), compiler-fenced
template <int N>
__device__ __forceinline__ void vm_wait() {
    if constexpr (N == 0) asm volatile("s_waitcnt vmcnt(0)" ::: "memory");
    else if constexpr (N == 1) asm volatile("s_waitcnt vmcnt(1)" ::: "memory");
    else if constexpr (N == 2) asm volatile("s_waitcnt vmcnt(2)" ::: "memory");
    else if constexpr (N == 3) asm volatile("s_waitcnt vmcnt(3)" ::: "memory");
    else if constexpr (N == 4) asm volatile("s_waitcnt vmcnt(4)" ::: "memory");
    else if constexpr (N == 6) asm volatile("s_waitcnt vmcnt(6)" ::: "memory");
    else if constexpr (N == 8) asm volatile("s_waitcnt vmcnt(8)" ::: "memory");
    else static_assert(N == 0, "unsupported vmcnt literal");
}
#define SBAR() asm volatile("s_barrier" ::: "memory")

// ---------------- fused prep: input fp32->bf16 hi/lo splits + 4 weight transpose-splits ----------------
__global__ __launch_bounds__(256) void prep_k(
    const float* __restrict__ q, const float* __restrict__ kv,
    u16* __restrict__ QXh, u16* __restrict__ QXl,
    u16* __restrict__ KVh, u16* __restrict__ KVl, long nblk, long n4,
    const float* __restrict__ Wq, const float* __restrict__ Wk,
    const float* __restrict__ Wv, const float* __restrict__ Wo,
    u16* __restrict__ WqTh, u16* __restrict__ WqTl,
    u16* __restrict__ WkvTh, u16* __restrict__ WkvTl,
    u16* __restrict__ WoTh, u16* __restrict__ WoTl, int dim) {
    long b = blockIdx.x;
    if (b < 2 * nblk) {
        const float* x = q; u16* h = QXh; u16* l = QXl;
        if (b >= nblk) { b -= nblk; x = kv; h = KVh; l = KVl; }
        long i = b * 256 + threadIdx.x;
        if (i >= n4) return;
        float4 v = ((const float4*)x)[i];
        float xs[4] = {v.x, v.y, v.z, v.w};
        u16 hh[4], ll[4];
#pragma unroll
        for (int qq = 0; qq < 4; ++qq) {
            hh[qq] = f2bf(xs[qq]);
            ll[qq] = f2bf(xs[qq] - bf2f(hh[qq]));
        }
        uint2 ph, pl;
        ph.x = hh[0] | ((u32)hh[1] << 16); ph.y = hh[2] | ((u32)hh[3] << 16);
        pl.x = ll[0] | ((u32)ll[1] << 16); pl.y = ll[2] | ((u32)ll[3] << 16);
        ((uint2*)h)[i] = ph;
        ((uint2*)l)[i] = pl;
        return;
    }
    long tb = b - 2 * nblk;
    const int z = (int)(tb >> 8);
    const int rem = (int)(tb & 255);
    const long DD = (long)dim * dim;
    const float* W; u16* Th; u16* Tl;
    switch (z) {
        case 0: W = Wq; Th = WqTh; Tl = WqTl; break;
        case 1: W = Wk; Th = WkvTh; Tl = WkvTl; break;
        case 2: W = Wv; Th = WkvTh + DD; Tl = WkvTl + DD; break;
        default: W = Wo; Th = WoTh; Tl = WoTl; break;
    }
    __shared__ float tile[32][33];
    const int bx = (rem & 15) * 32;
    const int by = (rem >> 4) * 32;
    const int tx = threadIdx.x & 31, ty = threadIdx.x >> 5;
    for (int i = 0; i < 32; i += 8)
        tile[ty + i][tx] = W[(size_t)(by + ty + i) * dim + bx + tx];
    __syncthreads();
    for (int i = 0; i < 32; i += 8) {
        float x = tile[tx][ty + i];
        u16 h = f2bf(x);
        size_t idx = (size_t)(bx + ty + i) * dim + by + tx;
        Th[idx] = h;
        Tl[idx] = f2bf(x - bf2f(h));
    }
}

// ---------------- row softmax, fp32 in, bf16 out in place ----------------
__global__ __launch_bounds__(256) void softmax_k(float* __restrict__ S, int N) {
    float* row = S + (size_t)blockIdx.x * N;
    const int t = threadIdx.x;
    float4 va = ((const float4*)row)[2 * t];
    float4 vb = ((const float4*)row)[2 * t + 1];
    float v[8] = {va.x, va.y, va.z, va.w, vb.x, vb.y, vb.z, vb.w};
    float m = v[0];
#pragma unroll
    for (int i = 1; i < 8; i++) m = fmaxf(m, v[i]);
#pragma unroll
    for (int o = 32; o; o >>= 1) m = fmaxf(m, __shfl_xor(m, o));
    __shared__ float smax[4], ssum[4];
    if ((t & 63) == 0) smax[t >> 6] = m;
    __syncthreads();
    m = fmaxf(fmaxf(smax[0], smax[1]), fmaxf(smax[2], smax[3]));
    float s = 0.f;
#pragma unroll
    for (int i = 0; i < 8; i++) { v[i] = __expf(v[i] - m); s += v[i]; }
#pragma unroll
    for (int o = 32; o; o >>= 1) s += __shfl_xor(s, o);
    if ((t & 63) == 0) ssum[t >> 6] = s;
    __syncthreads();
    s = ssum[0] + ssum[1] + ssum[2] + ssum[3];
    const float inv = 1.0f / s;
    u32 w0 = f2bf(v[0] * inv) | ((u32)f2bf(v[1] * inv) << 16);
    u32 w1 = f2bf(v[2] * inv) | ((u32)f2bf(v[3] * inv) << 16);
    u32 w2 = f2bf(v[4] * inv) | ((u32)f2bf(v[5] * inv) << 16);
    u32 w3 = f2bf(v[6] * inv) | ((u32)f2bf(v[7] * inv) << 16);
    uint4 o4; o4.x = w0; o4.y = w1; o4.z = w2; o4.w = w3;
    ((uint4*)row)[t] = o4;
}

// ---------------- MFMA GEMM, C = A @ BT^T ----------------
// v8 = v7 (v4 schedule: {vm_wait(N); SBAR; compute(ds_read+MFMA fused); SBAR; stage(t+2)})
// but with 8 WAVES per block (512 thr), wave tile 32x32 (WR=4 x WC=2).
// Rationale: LDS caps blocks/CU at 3 (48 KiB SPLIT) but not threads; 8 waves/block
// doubles resident waves (12 -> up to 24/CU) at identical LDS budget + schedule.
// Staging: A tile = BMt/16 = 8 GLD16-units -> 1 full-wave DMA per wave;
// B tile = BNt/16 = 4 units -> waves 0..3 only. Counted vmcnt is per-wave:
// hasB waves have 2x loads/stage -> wait literal {4:2} split, {2:1} non-split.
struct GemmArgs {
    const u16 *Ah, *Al; long lda, strideA;
    const u16 *BTh, *BTl; long ldb, strideBT;
    const float *bias1, *bias2; int nsplit;
    const float* resid; long ldres; float scale;
    float* Cf; long ldcf;
    u16 *Cbh, *Cbl; long ldcb;
    u16* CbT; long tRows, tChans, ldct;
    long strideC; int K;
};

template <int SPLIT, int BMt, int BNt>
struct SmemT {
    u16 AsH[2][BMt * BK];
    u16 BsH[2][BNt * BK];
    u16 AsL[2][(SPLIT ? BMt : 1) * BK];
    u16 BsL[2][(SPLIT ? BNt : 1) * BK];
};

template <int SPLIT, int BMt, int BNt, int WR, int WC>
__device__ __forceinline__ void gemm_body(SmemT<SPLIT, BMt, BNt>& sm, const GemmArgs& g,
                                          int bxi, int byi, long bz) {
    constexpr int WAVES = WR * WC;
    static_assert(WAVES == 8, "8-wave kernel");
    static_assert(BMt / 16 == WAVES, "A staging = 1 GLD16 per wave");
    constexpr int BW = BNt / 16;           // waves that also stage B
    static_assert(BW <= WAVES, "");
    constexpr int MI = BMt / WR / 16;
    constexpr int NJ = BNt / WC / 16;
    constexpr int NLD_B = 2 * (SPLIT ? 2 : 1);  // loads/stage for waves with B
    constexpr int NLD_A = (SPLIT ? 2 : 1);      // loads/stage for A-only waves

    const u16* Ah = g.Ah + bz * g.strideA;
    const u16* BTh = g.BTh + bz * g.strideBT;
    const u16* Al = nullptr; const u16* BTl = nullptr;
    if constexpr (SPLIT) { Al = g.Al + bz * g.strideA; BTl = g.BTl + bz * g.strideBT; }
    float* Cf = g.Cf ? g.Cf + bz * g.strideC : nullptr;
    u16* Cbh = g.Cbh ? g.Cbh + bz * g.strideC : nullptr;
    u16* Cbl = g.Cbl ? g.Cbl + bz * g.strideC : nullptr;

    const int t = threadIdx.x;
    const int w = t >> 6, lane = t & 63;
    const int l15 = lane & 15, quad = lane >> 4;
    const int m0 = bxi * BMt, n0 = byi * BNt;
    const int wrow = (w / WC) * (BMt / WR);
    const int wcol = (w % WC) * (BNt / WC);
    const bool hasB = (w < BW);

    // A staging: unit u = w*64+lane of BMt*4 16B-units; r = u>>2, c = u&3, swizzled col
    {
    }
    int uA = w * 64 + lane;
    int rA = uA >> 2, cA = uA & 3;
    int cgA = cA ^ ((rA >> 1) & 3);
    const u16* gAh = Ah + (long)(m0 + rA) * g.lda + cgA * 8;
    const u16* gAl = nullptr;
    if constexpr (SPLIT) gAl = Al + (long)(m0 + rA) * g.lda + cgA * 8;
    const int lA = (w * 64) * 8;  // u16 idx, wave-uniform LDS base
    // B staging (waves 0..BW-1): unit u = w*64+lane of BNt*4 units
    int uB = (hasB ? w : 0) * 64 + lane;
    int rB = uB >> 2, cB = uB & 3;
    int cgB = cB ^ ((rB >> 1) & 3);
    const u16* gBh = BTh + (long)(n0 + rB) * g.ldb + cgB * 8;
    const u16* gBl = nullptr;
    if constexpr (SPLIT) gBl = BTl + (long)(n0 + rB) * g.ldb + cgB * 8;
    const int lB = (w * 64) * 8;

    // fragment LDS offsets (u16 idx), constant across k-steps
    int aoff[MI], boff[NJ];
#pragma unroll
    for (int i = 0; i < MI; ++i) {
        int r = wrow + i * 16 + l15;
        aoff[i] = (r * 4 + (quad ^ ((r >> 1) & 3))) * 8;
    }
#pragma unroll
    for (int j = 0; j < NJ; ++j) {
        int r = wcol + j * 16 + l15;
        boff[j] = (r * 4 + (quad ^ ((r >> 1) & 3))) * 8;
    }

    f32x4 acc[MI][NJ];
#pragma unroll
    for (int i = 0; i < MI; i++)
#pragma unroll
        for (int j = 0; j < NJ; j++) acc[i][j] = (f32x4){0.f, 0.f, 0.f, 0.f};

    auto stage = [&](int buf) {
        GLD16(gAh, &sm.AsH[buf][lA]);
        gAh += BK;
        if constexpr (SPLIT) { GLD16(gAl, &sm.AsL[buf][lA]); gAl += BK; }
        if (hasB) {
            GLD16(gBh, &sm.BsH[buf][lB]);
            gBh += BK;
            if constexpr (SPLIT) { GLD16(gBl, &sm.BsL[buf][lB]); gBl += BK; }
        }
    };

    // ds_read fragments + MFMAs fused -- compiler schedules fine-grained lgkmcnt
    auto compute = [&](int buf) {
        bf16x8 aH[MI], bH[NJ];
#pragma unroll
        for (int i = 0; i < MI; ++i) aH[i] = *(const bf16x8*)&sm.AsH[buf][aoff[i]];
#pragma unroll
        for (int j = 0; j < NJ; ++j) bH[j] = *(const bf16x8*)&sm.BsH[buf][boff[j]];
        if constexpr (SPLIT) {
            bf16x8 aL[MI], bL[NJ];
#pragma unroll
            for (int i = 0; i < MI; ++i) aL[i] = *(const bf16x8*)&sm.AsL[buf][aoff[i]];
#pragma unroll
            for (int j = 0; j < NJ; ++j) bL[j] = *(const bf16x8*)&sm.BsL[buf][boff[j]];
#pragma unroll
            for (int i = 0; i < MI; ++i)
#pragma unroll
                for (int j = 0; j < NJ; ++j) {
                    acc[i][j] = __builtin_amdgcn_mfma_f32_16x16x32_bf16(aH[i], bH[j], acc[i][j], 0, 0, 0);
                    acc[i][j] = __builtin_amdgcn_mfma_f32_16x16x32_bf16(aH[i], bL[j], acc[i][j], 0, 0, 0);
                    acc[i][j] = __builtin_amdgcn_mfma_f32_16x16x32_bf16(aL[i], bH[j], acc[i][j], 0, 0, 0);
                }
        } else {
#pragma unroll
            for (int i = 0; i < MI; ++i)
#pragma unroll
                for (int j = 0; j < NJ; ++j)
                    acc[i][j] = __builtin_amdgcn_mfma_f32_16x16x32_bf16(aH[i], bH[j], acc[i][j], 0, 0, 0);
        }
    };

    const int nt = g.K / BK;  // >= 2 and even for all shapes used here
    stage(0);
    if (nt > 1) stage(1);
    for (int tt = 0; tt < nt; tt += 2) {
        // ---- tile tt in buf 0 ----
        if (tt + 1 < nt) {
            if (hasB) vm_wait<NLD_B>(); else vm_wait<NLD_A>();
        } else vm_wait<0>();
        SBAR();
        compute(0);
        SBAR();
        if (tt + 2 < nt) stage(0);
        // ---- tile tt+1 in buf 1 ----
        if (tt + 1 < nt) {
            if (tt + 2 < nt) {
                if (hasB) vm_wait<NLD_B>(); else vm_wait<NLD_A>();
            } else vm_wait<0>();
            SBAR();
            compute(1);
            SBAR();
            if (tt + 3 < nt) stage(1);
        }
    }

    // epilogue: C/D layout col=lane&15, row=quad*4+reg
#pragma unroll
    for (int i = 0; i < MI; ++i) {
#pragma unroll
        for (int j = 0; j < NJ; ++j) {
            const int mBase = m0 + wrow + i * 16 + quad * 4;
            const int nn = n0 + wcol + j * 16 + l15;
            const bool norm = nn < g.nsplit;
            float bvs;
            if (norm) bvs = g.bias1 ? g.bias1[nn] : 0.f;
            else bvs = g.bias2 ? g.bias2[nn - g.nsplit] : 0.f;
#pragma unroll
            for (int r = 0; r < 4; ++r) {
                const long row = mBase + r;
                float x = acc[i][j][r] * g.scale + bvs;
                if (g.resid) x += g.resid[row * g.ldres + nn];
                if (norm) {
                    if (Cf) Cf[row * g.ldcf + nn] = x;
                    if (Cbh) {
                        u16 h = f2bf(x);
                        Cbh[row * g.ldcb + nn] = h;
                        if (Cbl) Cbl[row * g.ldcb + nn] = f2bf(x - bf2f(h));
                    }
                } else {
                    long b = row / g.tRows, qq = row - b * g.tRows;
                    g.CbT[(b * g.tChans + (nn - g.nsplit)) * g.ldct + qq] = f2bf(x);
                }
            }
        }
    }
}

template <int SPLIT, int BMt, int BNt, int WR, int WC>
__global__ __launch_bounds__(512) void gemm_k(GemmArgs g) {
    __shared__ SmemT<SPLIT, BMt, BNt> sm;
    gemm_body<SPLIT, BMt, BNt, WR, WC>(sm, g, blockIdx.x, blockIdx.y, blockIdx.z);
}

// two independent GEMMs (same config) in one dispatch, y-concatenated
template <int SPLIT, int BMt, int BNt, int WR, int WC>
__global__ __launch_bounds__(512) void gemm2_k(GemmArgs g0, int ny0, GemmArgs g1) {
    __shared__ SmemT<SPLIT, BMt, BNt> sm;
    if ((int)blockIdx.y < ny0)
        gemm_body<SPLIT, BMt, BNt, WR, WC>(sm, g0, blockIdx.x, blockIdx.y, blockIdx.z);
    else
        gemm_body<SPLIT, BMt, BNt, WR, WC>(sm, g1, blockIdx.x, blockIdx.y - ny0, blockIdx.z);
}

extern "C" void kernel_launch(void* const* d_in, const int* in_sizes, int n_in,
                              void* d_out, int out_size, void* d_ws, size_t ws_size,
                              hipStream_t stream) {
    const float* query = (const float*)d_in[0];
    const float* kv    = (const float*)d_in[1];
    const float* Wq = (const float*)d_in[2];
    const float* bq = (const float*)d_in[3];
    const float* Wk = (const float*)d_in[4];
    const float* bk = (const float*)d_in[5];
    const float* Wv = (const float*)d_in[6];
    const float* bv = (const float*)d_in[7];
    const float* Wo = (const float*)d_in[8];
    const float* bo = (const float*)d_in[9];
    float* out = (float*)d_out;

    const int B = 4, N = 2048, D = 512;
    const long MD = (long)B * N * D;  // 4,194,304 (8192 rows x 512)
    const int BIG = 1 << 30;

    char* p = (char*)d_ws;
    auto alloc = [&](size_t bytes) { void* r = (void*)p; p += (bytes + 255) & ~(size_t)255; return r; };
    float* S = (float*)alloc((long)B * N * N * 4);   // 67 MB; fp32 scores, bf16 P in place
    u16* QXh = (u16*)S;                               // input splits alias S (dead before S written)
    u16* QXl = QXh + MD;
    u16* KVh = QXl + MD;
    u16* KVl = KVh + MD;
    u16* Qh = (u16*)alloc(MD * 2);
    u16* Ql = (u16*)alloc(MD * 2);
    u16* Kh = (u16*)alloc(MD * 2);
    u16* Kl = (u16*)alloc(MD * 2);
    u16* Vt = (u16*)alloc(MD * 2);                    // [B][D][N]
    u16* Oh = (u16*)alloc(MD * 2);
    u16* WqTh = (u16*)alloc((long)D * D * 2);
    u16* WqTl = (u16*)alloc((long)D * D * 2);
    u16* WkvTh = (u16*)alloc((long)2 * D * D * 2);
    u16* WkvTl = (u16*)alloc((long)2 * D * D * 2);
    u16* WoTh = (u16*)alloc((long)D * D * 2);
    u16* WoTl = (u16*)alloc((long)D * D * 2);

    const dim3 blk(256, 1, 1);
    const dim3 blk8(512, 1, 1);
    const float SCALE = 22.627416997969522f;  // sqrt(512), multiplied per reference

    prep_k<<<dim3(2 * 4096 + 1024, 1, 1), blk, 0, stream>>>(
        query, kv, QXh, QXl, KVh, KVl, 4096, MD / 4,
        Wq, Wk, Wv, Wo, WqTh, WqTl, WkvTh, WkvTl, WoTh, WoTl, D);

    // merged Q-proj (y<8) + KV-proj (y>=8)
    GemmArgs qa{};
    qa.Ah = QXh; qa.Al = QXl; qa.lda = D; qa.strideA = 0;
    qa.BTh = WqTh; qa.BTl = WqTl; qa.ldb = D; qa.strideBT = 0;
    qa.bias1 = bq; qa.bias2 = nullptr; qa.nsplit = BIG;
    qa.resid = nullptr; qa.ldres = 0; qa.scale = 1.0f;
    qa.Cf = nullptr; qa.ldcf = 0;
    qa.Cbh = Qh; qa.Cbl = Ql; qa.ldcb = D;
    qa.CbT = nullptr; qa.tRows = 1; qa.tChans = 1; qa.ldct = 1;
    qa.strideC = 0; qa.K = D;

    GemmArgs ka{};
    ka.Ah = KVh; ka.Al = KVl; ka.lda = D; ka.strideA = 0;
    ka.BTh = WkvTh; ka.BTl = WkvTl; ka.ldb = D; ka.strideBT = 0;
    ka.bias1 = bk; ka.bias2 = bv; ka.nsplit = D;
    ka.resid = nullptr; ka.ldres = 0; ka.scale = 1.0f;
    ka.Cf = nullptr; ka.ldcf = 0;
    ka.Cbh = Kh; ka.Cbl = Kl; ka.ldcb = D;
    ka.CbT = Vt; ka.tRows = N; ka.tChans = D; ka.ldct = N;
    ka.strideC = 0; ka.K = D;
    gemm2_k<1, 128, 64, 4, 2><<<dim3(64, 24, 1), blk8, 0, stream>>>(qa, 8, ka);

    // S = SCALE * Q @ K^T  [128x64 SPLIT, 48 KiB, 8 waves]
    GemmArgs sa{};
    sa.Ah = Qh; sa.Al = Ql; sa.lda = D; sa.strideA = (long)N * D;
    sa.BTh = Kh; sa.BTl = Kl; sa.ldb = D; sa.strideBT = (long)N * D;
    sa.bias1 = nullptr; sa.bias2 = nullptr; sa.nsplit = BIG;
    sa.resid = nullptr; sa.ldres = 0; sa.scale = SCALE;
    sa.Cf = S; sa.ldcf = N;
    sa.Cbh = nullptr; sa.Cbl = nullptr; sa.ldcb = 0;
    sa.CbT = nullptr; sa.tRows = 1; sa.tChans = 1; sa.ldct = 1;
    sa.strideC = (long)N * N; sa.K = D;
    gemm_k<1, 128, 64, 4, 2><<<dim3(16, 32, 4), blk8, 0, stream>>>(sa);

    softmax_k<<<dim3(B * N, 1, 1), blk, 0, stream>>>(S, N);

    // O = P @ V  [128x64 non-split, K=2048, 8 waves -> up to 4 blocks/CU]
    GemmArgs pa{};
    pa.Ah = (const u16*)S; pa.Al = nullptr; pa.lda = 2L * N; pa.strideA = (long)N * 2 * N;
    pa.BTh = Vt; pa.BTl = nullptr; pa.ldb = N; pa.strideBT = (long)D * N;
    pa.bias1 = nullptr; pa.bias2 = nullptr; pa.nsplit = BIG;
    pa.resid = nullptr; pa.ldres = 0; pa.scale = 1.0f;
    pa.Cf = nullptr; pa.ldcf = 0;
    pa.Cbh = Oh; pa.Cbl = nullptr; pa.ldcb = D;
    pa.CbT = nullptr; pa.tRows = 1; pa.tChans = 1; pa.ldct = 1;
    pa.strideC = (long)N * D; pa.K = N;
    gemm_k<0, 128, 64, 4, 2><<<dim3(16, 8, 4), blk8, 0, stream>>>(pa);

    // out = query + O @ Wo + bo
    GemmArgs oa{};
    oa.Ah = Oh; oa.Al = nullptr; oa.lda = D; oa.strideA = 0;
    oa.BTh = WoTh; oa.BTl = nullptr; oa.ldb = D; oa.strideBT = 0;
    oa.bias1 = bo; oa.bias2 = nullptr; oa.nsplit = BIG;
    oa.resid = query; oa.ldres = D; oa.scale = 1.0f;
    oa.Cf = out; oa.ldcf = D;
    oa.Cbh = nullptr; oa.Cbl = nullptr; oa.ldcb = 0;
    oa.CbT = nullptr; oa.tRows = 1; oa.tChans = 1; oa.ldct = 1;
    oa.strideC = 0; oa.K = D;
    gemm_k<0, 128, 64, 4, 2><<<dim3(64, 8, 1), blk8, 0, stream>>>(oa);

    (void)in_sizes; (void)n_in; (void)out_size; (void)ws_size;
}